// Round 1
// 103.083 us; speedup vs baseline: 1.0021x; 1.0021x over previous
//
#include <hip/hip_runtime.h>

#define NTOK 1048576
#define HID 64
#define TPB 256
#define TPB_TOK 1024
#define RPT (TPB_TOK / TPB)          // 4 tokens per thread in phase A/C
#define NBLK (NTOK / TPB_TOK)        // 1024 blocks = exactly 4 blocks/CU resident
#define MAXSLOT (TPB_TOK + 64)       // binned slots incl. 16-pad per expert
#define MAXTILE (TPB_TOK / 16 + 4)

typedef _Float16 half8 __attribute__((ext_vector_type(8)));
typedef _Float16 half4 __attribute__((ext_vector_type(4)));
typedef _Float16 half2v __attribute__((ext_vector_type(2)));
typedef float f32x4 __attribute__((ext_vector_type(4)));

static __device__ __forceinline__ half2v pkh(float a, float b) {
    return __builtin_bit_cast(half2v, __builtin_amdgcn_cvt_pkrtz(a, b));
}

// f32 += dot(half2, half2) — v_dot2_f32_f16 on gfx950
static __device__ __forceinline__ float fdot2f(half2v a, half2v b, float c) {
#if __has_builtin(__builtin_amdgcn_fdot2)
    return __builtin_amdgcn_fdot2(a, b, c, false);
#else
    return c + (float)a.x * (float)b.x + (float)a.y * (float)b.y;
#endif
}

// Convert w2 (E,HID,HID) fp32 -> f16 MFMA A-operand fragments for the
// transposed GEMM h2^T = w2^T @ h1^T.
// A[m=hid_out][k=hid_in]; frag elem (e, mt, ks, lane, j):
//   m = mt*16 + (lane&15), k = ks*32 + (lane>>4)*8 + j  -> w2[e][k][m]
__global__ void prep_w2_frag(const float* __restrict__ w2, _Float16* __restrict__ wsf) {
    int idx  = blockIdx.x * 256 + threadIdx.x;   // 0..16383
    int j    = idx & 7;
    int lane = (idx >> 3) & 63;
    int ks   = (idx >> 9) & 1;
    int mt   = (idx >> 10) & 3;
    int e    = idx >> 12;
    int kin  = ks * 32 + (lane >> 4) * 8 + j;
    int m    = mt * 16 + (lane & 15);
    wsf[idx] = (_Float16)w2[(e * HID + kin) * HID + m];
}

__global__ __launch_bounds__(TPB, 4) void moe_kernel(
    const float* __restrict__ x, const float* __restrict__ rW, const float* __restrict__ rb,
    const float* __restrict__ w1, const float* __restrict__ b1,
    const float* __restrict__ b2,
    const float* __restrict__ w3, const float* __restrict__ b3,
    const _Float16* __restrict__ wsf, float* __restrict__ out)
{
    __shared__ float2 xs[MAXSLOT];              // x in phase B, reused as y for phase C
    __shared__ int wcnt[4][4];                  // [wave][expert]
    __shared__ int seg_start[4], cumt[5];
    __shared__ unsigned tmap[MAXTILE];
    // packed-f16 per-expert weight staging (broadcast-read in phase B)
    __shared__ __align__(16) half2v l_w1[4][2][32];   // [e][dim][hid pair]
    __shared__ __align__(16) half2v l_b1[4][32];
    __shared__ __align__(16) half2v l_b2[4][32];
    __shared__ __align__(16) half2v l_w3c[4][2][32];  // [e][out c][pair r/2]=(w3[2i][c],w3[2i+1][c])
    __shared__ float2 l_b3[4];

    const int t = threadIdx.x, w = t >> 6, lane = t & 63;
    const int base = blockIdx.x * TPB_TOK;
    const unsigned long long lt = (1ull << lane) - 1ull;

    // ---------------- weight staging (once per block, before first barrier) ----------------
    {
        int e = t >> 6, i = t & 63;
        float2 v1 = ((const float2*)(w1 + e * 128))[i];
        l_w1[e][i >> 5][i & 31] = pkh(v1.x, v1.y);
        if (i < 32) {
            float2 vb = ((const float2*)(b1 + e * 64))[i];
            l_b1[e][i] = pkh(vb.x, vb.y);
            float2 v2 = ((const float2*)(b2 + e * 64))[i];
            l_b2[e][i] = pkh(v2.x, v2.y);
        } else {
            int ii = i - 32;
            float4 wv = ((const float4*)(w3 + e * 128))[ii]; // rows 2ii,2ii+1 (both cols)
            l_w3c[e][0][ii] = pkh(wv.x, wv.z);
            l_w3c[e][1][ii] = pkh(wv.y, wv.w);
        }
        if (t < 4) l_b3[t] = ((const float2*)b3)[t];
    }

    // ---------------- Phase A: router + binning (argmax logic bit-identical) ----------------
    const float r00 = rW[0], r01 = rW[1], r02 = rW[2], r03 = rW[3];
    const float r10 = rW[4], r11 = rW[5], r12 = rW[6], r13 = rW[7];
    const float rb0 = rb[0], rb1 = rb[1], rb2 = rb[2], rb3 = rb[3];

    int c0 = 0, c1 = 0, c2 = 0, c3 = 0;
    int slotl[RPT]; int bestl[RPT]; float2 xv_[RPT]; int slotf[RPT];
    float* logits_out = out + 2 * NTOK;
    #pragma unroll
    for (int i = 0; i < RPT; i++) {
        int tok = base + i * TPB + t;
        float2 xv = ((const float2*)x)[tok];
        float l0 = xv.x * r00 + xv.y * r10 + rb0;
        float l1 = xv.x * r01 + xv.y * r11 + rb1;
        float l2 = xv.x * r02 + xv.y * r12 + rb2;
        float l3 = xv.x * r03 + xv.y * r13 + rb3;
        ((float4*)logits_out)[tok] = make_float4(l0, l1, l2, l3);
        int b = 0; float bv = l0;
        if (l1 > bv) { bv = l1; b = 1; }
        if (l2 > bv) { bv = l2; b = 2; }
        if (l3 > bv) { bv = l3; b = 3; }
        unsigned long long m0 = __ballot(b == 0), m1 = __ballot(b == 1),
                           m2 = __ballot(b == 2), m3 = __ballot(b == 3);
        unsigned long long mym = (b == 0) ? m0 : (b == 1) ? m1 : (b == 2) ? m2 : m3;
        int cb = (b == 0) ? c0 : (b == 1) ? c1 : (b == 2) ? c2 : c3;
        slotl[i] = cb + __popcll(mym & lt);
        bestl[i] = b; xv_[i] = xv;
        c0 += __popcll(m0); c1 += __popcll(m1); c2 += __popcll(m2); c3 += __popcll(m3);
    }
    if (lane < 4) wcnt[w][lane] = (lane == 0) ? c0 : (lane == 1) ? c1 : (lane == 2) ? c2 : c3;
    __syncthreads();
    if (t == 0) {
        int run = 0, ct = 0; cumt[0] = 0;
        for (int e = 0; e < 4; e++) {
            int c = wcnt[0][e] + wcnt[1][e] + wcnt[2][e] + wcnt[3][e];
            seg_start[e] = run;
            run += (c + 15) & ~15; ct += (c + 15) >> 4; cumt[e + 1] = ct;
        }
    }
    __syncthreads();
    int wo0 = 0, wo1 = 0, wo2 = 0, wo3 = 0;
    for (int ww = 0; ww < w; ww++) {
        wo0 += wcnt[ww][0]; wo1 += wcnt[ww][1]; wo2 += wcnt[ww][2]; wo3 += wcnt[ww][3];
    }
    #pragma unroll
    for (int i = 0; i < RPT; i++) {
        int b = bestl[i];
        int wo = (b == 0) ? wo0 : (b == 1) ? wo1 : (b == 2) ? wo2 : wo3;
        int slot = seg_start[b] + wo + slotl[i];
        xs[slot] = xv_[i];
        slotf[i] = slot;
    }
    int T = cumt[4];
    for (int g = t; g < T; g += TPB) {
        int e = (g >= cumt[1]) + (g >= cumt[2]) + (g >= cumt[3]);
        int i = g - cumt[e];
        int row = seg_start[e] + 16 * i;
        tmap[g] = (unsigned)e | ((unsigned)row << 2);
    }
    __syncthreads();

    // ---------------- Phase B: per-tile MFMA ----------------
    const int q = lane >> 4, n16 = lane & 15;
    int chunk = (T + 3) >> 2;
    int g0 = w * chunk, g1 = g0 + chunk; if (g1 > T) g1 = T;

    // persistent per-expert state: only the MFMA A-fragments + b3
    half8 w2A[4][2];                   // 32 VGPR
    float2 b3r = make_float2(0.f, 0.f);
    int cur_e = -1;
    const half2v hz = { (_Float16)0, (_Float16)0 };
    const half8 hz8 = { (_Float16)0, (_Float16)0, (_Float16)0, (_Float16)0,
                        (_Float16)0, (_Float16)0, (_Float16)0, (_Float16)0 };

    // prefetch pipeline for tile metadata + x
    unsigned tm_n = 0; float2 xv_n = make_float2(0.f, 0.f);
    if (g0 < g1) {
        tm_n = tmap[g0];
        xv_n = xs[((tm_n >> 2) & 0xFFF) + n16];
    }

    for (int g = g0; g < g1; g++) {
        unsigned tm = tm_n; float2 xv = xv_n;
        if (g + 1 < g1) {
            tm_n = tmap[g + 1];
            xv_n = xs[((tm_n >> 2) & 0xFFF) + n16];
        }
        int e   = tm & 3;
        int row = (tm >> 2) & 0xFFF;
        if (e != cur_e) {   // wave-uniform, <=4x per wave (tiles expert-sorted)
            cur_e = e;
            #pragma unroll
            for (int mt = 0; mt < 4; mt++) {
                w2A[mt][0] = ((const half8*)wsf)[((e * 4 + mt) * 2 + 0) * 64 + lane];
                w2A[mt][1] = ((const half8*)wsf)[((e * 4 + mt) * 2 + 1) * 64 + lane];
            }
            b3r = l_b3[e];
        }
        // h1 weights from LDS (broadcast within each 16-lane q-group)
        const int q4 = q * 4;
        half8 wa_lo = *(const half8*)&l_w1[e][0][q4];        // hid q*8..q*8+7, dim0
        half8 wa_hi = *(const half8*)&l_w1[e][0][16 + q4];   // hid 32+q*8.., dim0
        half8 wb_lo = *(const half8*)&l_w1[e][1][q4];
        half8 wb_hi = *(const half8*)&l_w1[e][1][16 + q4];
        half8 b1lo  = *(const half8*)&l_b1[e][q4];
        half8 b1hi  = *(const half8*)&l_b1[e][16 + q4];
        // h1 lands directly in B-fragment layout: B[k = ks*32 + q*8 + j][n = n16]
        _Float16 xa = (_Float16)xv.x, xb = (_Float16)xv.y;
        half8 bf0 = wa_lo * xa + wb_lo * xb + b1lo;
        half8 bf1 = wa_hi * xa + wb_hi * xb + b1hi;
        bf0 = __builtin_elementwise_max(bf0, hz8);
        bf1 = __builtin_elementwise_max(bf1, hz8);

        // layer 2 MFMA + dot2-based layer 3 epilogue, f32 accumulators
        float y0 = 0.f, y1 = 0.f;
        #pragma unroll
        for (int mt = 0; mt < 4; mt++) {
            // per-mt epilogue weights (LDS b64 reads, issued before the MFMAs)
            half4 b2v  = *(const half4*)&l_b2[e][mt * 8 + q * 2];
            half4 w3c0 = *(const half4*)&l_w3c[e][0][mt * 8 + q * 2];
            half4 w3c1 = *(const half4*)&l_w3c[e][1][mt * 8 + q * 2];
            f32x4 acc = {0.f, 0.f, 0.f, 0.f};
            acc = __builtin_amdgcn_mfma_f32_16x16x32_f16(w2A[mt][0], bf0, acc, 0, 0, 0);
            acc = __builtin_amdgcn_mfma_f32_16x16x32_f16(w2A[mt][1], bf1, acc, 0, 0, 0);
            // C-frag: col(token)=n16, row(hid_out)=mt*16+q*4+i
            half2v b2a = __builtin_shufflevector(b2v, b2v, 0, 1);
            half2v b2b = __builtin_shufflevector(b2v, b2v, 2, 3);
            half2v h01 = __builtin_elementwise_max(pkh(acc[0], acc[1]) + b2a, hz);
            half2v h23 = __builtin_elementwise_max(pkh(acc[2], acc[3]) + b2b, hz);
            half2v w30a = __builtin_shufflevector(w3c0, w3c0, 0, 1);
            half2v w30b = __builtin_shufflevector(w3c0, w3c0, 2, 3);
            half2v w31a = __builtin_shufflevector(w3c1, w3c1, 0, 1);
            half2v w31b = __builtin_shufflevector(w3c1, w3c1, 2, 3);
            y0 = fdot2f(h01, w30a, y0);
            y0 = fdot2f(h23, w30b, y0);
            y1 = fdot2f(h01, w31a, y1);
            y1 = fdot2f(h23, w31b, y1);
        }
        // reduce over the 4 lane-quads (hid_out split)
        y0 += __shfl_xor(y0, 16); y0 += __shfl_xor(y0, 32);
        y1 += __shfl_xor(y1, 16); y1 += __shfl_xor(y1, 32);
        if (q == 0) {
            xs[row + n16] = make_float2(y0 + b3r.x, y1 + b3r.y);  // y overwrites consumed x
        }
    }
    __syncthreads();

    // ---------------- Phase C: coalesced output ----------------
    #pragma unroll
    for (int i = 0; i < RPT; i++) {
        ((float2*)out)[base + i * TPB + t] = xs[slotf[i]];
    }
}

extern "C" void kernel_launch(void* const* d_in, const int* in_sizes, int n_in,
                              void* d_out, int out_size, void* d_ws, size_t ws_size,
                              hipStream_t stream) {
    const float* x  = (const float*)d_in[0];
    const float* rW = (const float*)d_in[1];
    const float* rb = (const float*)d_in[2];
    const float* w1 = (const float*)d_in[3];
    const float* b1 = (const float*)d_in[4];
    const float* w2 = (const float*)d_in[5];
    const float* b2 = (const float*)d_in[6];
    const float* w3 = (const float*)d_in[7];
    const float* b3 = (const float*)d_in[8];
    float* out = (float*)d_out;
    _Float16* wsf = (_Float16*)d_ws;

    hipLaunchKernelGGL(prep_w2_frag, dim3(64), dim3(256), 0, stream, w2, wsf);
    hipLaunchKernelGGL(moe_kernel, dim3(NBLK), dim3(TPB), 0, stream,
                       x, rW, rb, w1, b1, b2, w3, b3, (const _Float16*)wsf, out);
}